// Round 1
// baseline (313.789 us; speedup 1.0000x reference)
//
#include <hip/hip_runtime.h>
#include <math.h>

#define NB 2
#define NL 256
#define NH 768
#define NI 1536
#define NM (NB * NL)   // 512

// ---------------------------------------------------------------------------
// Kernel 1: start/end logits. One block per row m (=b*L+s), 256 threads.
// ---------------------------------------------------------------------------
__global__ __launch_bounds__(256) void logits_kernel(
    const float* __restrict__ hs,
    const float* __restrict__ sw, const float* __restrict__ sb,
    const float* __restrict__ ew, const float* __restrict__ eb,
    float* __restrict__ out) {
  int m = blockIdx.x;
  int tid = threadIdx.x;
  const float* row = hs + (size_t)m * NH;
  float accs = 0.f, acce = 0.f;
  for (int h = tid; h < NH; h += 256) {
    float v = row[h];
    accs = fmaf(v, sw[h], accs);
    acce = fmaf(v, ew[h], acce);
  }
  // wave64 reduce
  for (int off = 32; off > 0; off >>= 1) {
    accs += __shfl_down(accs, off, 64);
    acce += __shfl_down(acce, off, 64);
  }
  __shared__ float s_s[4], s_e[4];
  int wid = tid >> 6;
  if ((tid & 63) == 0) { s_s[wid] = accs; s_e[wid] = acce; }
  __syncthreads();
  if (tid == 0) {
    float ts = s_s[0] + s_s[1] + s_s[2] + s_s[3];
    float te = s_e[0] + s_e[1] + s_e[2] + s_e[3];
    out[m]      = ts + sb[0];
    out[NM + m] = te + eb[0];
  }
}

// ---------------------------------------------------------------------------
// Kernel 2: GEMM  OUT(M x I) = hs(M x H) @ W(H x I)
// MODE 0: a = hs @ w1[:H] + b1, row-major  a[m*I + i]
// MODE 1: c = hs @ w1[H:],    transposed  cT[b*I*L + i*L + t]  (m = b*L + t)
// 64x64 tile, BK=16, 256 threads, 4x4 accum per thread.
// ---------------------------------------------------------------------------
template <int MODE>
__global__ __launch_bounds__(256) void gemm_kernel(
    const float* __restrict__ hs,
    const float* __restrict__ w1,
    const float* __restrict__ b1,
    float* __restrict__ out) {
  constexpr int BM = 64, BN = 64, BK = 16;
  __shared__ float As[BK][BM];
  __shared__ float Bs[BK][BN];

  const float* W = w1 + (MODE ? (size_t)NH * NI : 0);
  int m0 = blockIdx.x * BM;
  int n0 = blockIdx.y * BN;
  int tid = threadIdx.x;
  int ty = tid >> 4;        // 0..15
  int tx = tid & 15;        // 0..15

  // A-tile load mapping: 64 rows x 16 cols, thread -> (row=tid>>2, col4=(tid&3)*4)
  int ar = tid >> 2;
  int ac = (tid & 3) * 4;
  // B-tile load mapping: 16 rows x 64 cols, thread -> (row=tid>>4, col4=(tid&15)*4)
  int br = tid >> 4;
  int bc = (tid & 15) * 4;

  float acc[4][4] = {};

  for (int k0 = 0; k0 < NH; k0 += BK) {
    float4 av = *reinterpret_cast<const float4*>(hs + (size_t)(m0 + ar) * NH + k0 + ac);
    float4 bv = *reinterpret_cast<const float4*>(W + (size_t)(k0 + br) * NI + n0 + bc);
    __syncthreads();
    As[ac + 0][ar] = av.x;
    As[ac + 1][ar] = av.y;
    As[ac + 2][ar] = av.z;
    As[ac + 3][ar] = av.w;
    *reinterpret_cast<float4*>(&Bs[br][bc]) = bv;
    __syncthreads();
#pragma unroll
    for (int k = 0; k < BK; ++k) {
      float4 af = *reinterpret_cast<const float4*>(&As[k][ty * 4]);
      float4 bf = *reinterpret_cast<const float4*>(&Bs[k][tx * 4]);
      float aa[4] = {af.x, af.y, af.z, af.w};
      float bb[4] = {bf.x, bf.y, bf.z, bf.w};
#pragma unroll
      for (int ii = 0; ii < 4; ++ii)
#pragma unroll
        for (int jj = 0; jj < 4; ++jj)
          acc[ii][jj] = fmaf(aa[ii], bb[jj], acc[ii][jj]);
    }
  }

  if (MODE == 0) {
    // a[m*I + i] with b1 folded in
#pragma unroll
    for (int ii = 0; ii < 4; ++ii) {
      int m = m0 + ty * 4 + ii;
      int col = n0 + tx * 4;
      float4 v;
      v.x = acc[ii][0] + b1[col + 0];
      v.y = acc[ii][1] + b1[col + 1];
      v.z = acc[ii][2] + b1[col + 2];
      v.w = acc[ii][3] + b1[col + 3];
      *reinterpret_cast<float4*>(out + (size_t)m * NI + col) = v;
    }
  } else {
    // cT[b*I*L + i*L + t] ; all rows of this block share one b (BM=64 | L=256)
    int b = m0 >> 8;
    int t0 = (m0 & (NL - 1)) + ty * 4;
#pragma unroll
    for (int jj = 0; jj < 4; ++jj) {
      int col = n0 + tx * 4 + jj;
      float4 v;
      v.x = acc[0][jj];
      v.y = acc[1][jj];
      v.z = acc[2][jj];
      v.w = acc[3][jj];
      *reinterpret_cast<float4*>(out + (size_t)b * NI * NL + (size_t)col * NL + t0) = v;
    }
  }
}

// ---------------------------------------------------------------------------
// Kernel 3: span logits. Block = (b,s), thread = t.
// span[bs*L + t] = sum_i gelu(aRow[bs,i] + cT[b,i,t]) * w2[i] + b2
// ---------------------------------------------------------------------------
__global__ __launch_bounds__(256) void span_kernel(
    const float* __restrict__ aRow,   // [M][I], b1 folded
    const float* __restrict__ cT,     // [B][I][L]
    const float* __restrict__ w2,
    const float* __restrict__ b2,
    float* __restrict__ out) {
  int bs = blockIdx.x;     // b*L + s
  int b = bs >> 8;
  int t = threadIdx.x;

  __shared__ float a_lds[NI];
  __shared__ float w_lds[NI];
  for (int i = t; i < NI; i += 256) {
    a_lds[i] = aRow[(size_t)bs * NI + i];
    w_lds[i] = w2[i];
  }
  __syncthreads();

  const float* cb = cT + (size_t)b * NI * NL + t;
  float acc0 = 0.f, acc1 = 0.f, acc2 = 0.f, acc3 = 0.f;
  constexpr float kInvSqrt2 = 0.70710678118654752440f;
#pragma unroll 4
  for (int i = 0; i < NI; i += 4) {
    float x0 = a_lds[i + 0] + cb[(size_t)(i + 0) * NL];
    float x1 = a_lds[i + 1] + cb[(size_t)(i + 1) * NL];
    float x2 = a_lds[i + 2] + cb[(size_t)(i + 2) * NL];
    float x3 = a_lds[i + 3] + cb[(size_t)(i + 3) * NL];
    float g0 = 0.5f * x0 * (1.0f + erff(x0 * kInvSqrt2));
    float g1 = 0.5f * x1 * (1.0f + erff(x1 * kInvSqrt2));
    float g2 = 0.5f * x2 * (1.0f + erff(x2 * kInvSqrt2));
    float g3 = 0.5f * x3 * (1.0f + erff(x3 * kInvSqrt2));
    acc0 = fmaf(g0, w_lds[i + 0], acc0);
    acc1 = fmaf(g1, w_lds[i + 1], acc1);
    acc2 = fmaf(g2, w_lds[i + 2], acc2);
    acc3 = fmaf(g3, w_lds[i + 3], acc3);
  }
  out[2 * NM + (size_t)bs * NL + t] = (acc0 + acc1) + (acc2 + acc3) + b2[0];
}

// ---------------------------------------------------------------------------
extern "C" void kernel_launch(void* const* d_in, const int* in_sizes, int n_in,
                              void* d_out, int out_size, void* d_ws, size_t ws_size,
                              hipStream_t stream) {
  const float* hs = (const float*)d_in[0];
  const float* sw = (const float*)d_in[1];
  const float* sb = (const float*)d_in[2];
  const float* ew = (const float*)d_in[3];
  const float* eb = (const float*)d_in[4];
  const float* w1 = (const float*)d_in[5];
  const float* b1 = (const float*)d_in[6];
  const float* w2 = (const float*)d_in[7];
  const float* b2 = (const float*)d_in[8];
  float* out = (float*)d_out;

  float* a  = (float*)d_ws;                                  // M*I floats = 3 MB
  float* cT = (float*)d_ws + (size_t)NM * NI;                // B*I*L floats = 3 MB

  logits_kernel<<<NM, 256, 0, stream>>>(hs, sw, sb, ew, eb, out);

  dim3 ggrid(NM / 64, NI / 64);
  gemm_kernel<0><<<ggrid, 256, 0, stream>>>(hs, w1, b1, a);
  gemm_kernel<1><<<ggrid, 256, 0, stream>>>(hs, w1, b1, cT);

  span_kernel<<<NM, 256, 0, stream>>>(a, cT, w2, b2, out);
}

// Round 2
// 119.191 us; speedup vs baseline: 2.6327x; 2.6327x over previous
//
#include <hip/hip_runtime.h>
#include <math.h>

#define NB 2
#define NL 256
#define NH 768
#define NI 1536
#define NI4 (NI / 4)
#define NM (NB * NL)   // 512

// ---------------------------------------------------------------------------
// fast gelu: x * sigmoid(1.5957691(x + 0.044715 x^3)), evaluated via 2^z.
// z_neg = -x*(2.3022082 + 0.1029434*x^2)   [log2(e) folded into constants]
// ---------------------------------------------------------------------------
#if __has_builtin(__builtin_amdgcn_exp2f)
#define FAST_EXP2(x) __builtin_amdgcn_exp2f(x)
#else
#define FAST_EXP2(x) exp2f(x)
#endif
#if __has_builtin(__builtin_amdgcn_rcpf)
#define FAST_RCP(x) __builtin_amdgcn_rcpf(x)
#else
#define FAST_RCP(x) (1.0f / (x))
#endif

__device__ __forceinline__ float fast_gelu(float x) {
  float u = x * x;
  float zn = x * fmaf(u, -0.1029434f, -2.3022082f);
  float e = FAST_EXP2(zn);               // 2^(-1.4427*1.5958*(x+0.044715x^3))
  return x * FAST_RCP(1.0f + e);
}

// ---------------------------------------------------------------------------
// Kernel 1: start/end logits. One block per row m (=b*L+s), 256 threads.
// ---------------------------------------------------------------------------
__global__ __launch_bounds__(256) void logits_kernel(
    const float* __restrict__ hs,
    const float* __restrict__ sw, const float* __restrict__ sb,
    const float* __restrict__ ew, const float* __restrict__ eb,
    float* __restrict__ out) {
  int m = blockIdx.x;
  int tid = threadIdx.x;
  const float* row = hs + (size_t)m * NH;
  float accs = 0.f, acce = 0.f;
  for (int h = tid; h < NH; h += 256) {
    float v = row[h];
    accs = fmaf(v, sw[h], accs);
    acce = fmaf(v, ew[h], acce);
  }
  for (int off = 32; off > 0; off >>= 1) {
    accs += __shfl_down(accs, off, 64);
    acce += __shfl_down(acce, off, 64);
  }
  __shared__ float s_s[4], s_e[4];
  int wid = tid >> 6;
  if ((tid & 63) == 0) { s_s[wid] = accs; s_e[wid] = acce; }
  __syncthreads();
  if (tid == 0) {
    float ts = s_s[0] + s_s[1] + s_s[2] + s_s[3];
    float te = s_e[0] + s_e[1] + s_e[2] + s_e[3];
    out[m]      = ts + sb[0];
    out[NM + m] = te + eb[0];
  }
}

// ---------------------------------------------------------------------------
// Kernel 2: GEMM  OUT(M x I) = hs(M x H) @ W(H x I), both halves of w1 in one
// launch (MODE = blockIdx.z).
// MODE 0: a[m*I + i] = hs @ w1[:H] + b1  (row-major)
// MODE 1: c4[b][i/4][t] (float4 over i) = hs @ w1[H:]   (m = b*L + t)
// 64x64 tile, BK=16, 256 threads, 4x4 accum per thread.
// ---------------------------------------------------------------------------
__global__ __launch_bounds__(256) void gemm_kernel(
    const float* __restrict__ hs,
    const float* __restrict__ w1,
    const float* __restrict__ b1,
    float* __restrict__ outA,
    float4* __restrict__ outC4) {
  constexpr int BM = 64, BN = 64, BK = 16;
  __shared__ float As[BK][BM];
  __shared__ float Bs[BK][BN];

  const int MODE = blockIdx.z;
  const float* W = w1 + (MODE ? (size_t)NH * NI : 0);
  int m0 = blockIdx.x * BM;
  int n0 = blockIdx.y * BN;
  int tid = threadIdx.x;
  int ty = tid >> 4;        // 0..15
  int tx = tid & 15;        // 0..15

  int ar = tid >> 2;        // A row 0..63
  int ac = (tid & 3) * 4;   // A col group
  int br = tid >> 4;        // B row 0..15
  int bc = (tid & 15) * 4;  // B col group

  float acc[4][4] = {};

  for (int k0 = 0; k0 < NH; k0 += BK) {
    float4 av = *reinterpret_cast<const float4*>(hs + (size_t)(m0 + ar) * NH + k0 + ac);
    float4 bv = *reinterpret_cast<const float4*>(W + (size_t)(k0 + br) * NI + n0 + bc);
    __syncthreads();
    As[ac + 0][ar] = av.x;
    As[ac + 1][ar] = av.y;
    As[ac + 2][ar] = av.z;
    As[ac + 3][ar] = av.w;
    *reinterpret_cast<float4*>(&Bs[br][bc]) = bv;
    __syncthreads();
#pragma unroll
    for (int k = 0; k < BK; ++k) {
      float4 af = *reinterpret_cast<const float4*>(&As[k][ty * 4]);
      float4 bf = *reinterpret_cast<const float4*>(&Bs[k][tx * 4]);
      float aa[4] = {af.x, af.y, af.z, af.w};
      float bb[4] = {bf.x, bf.y, bf.z, bf.w};
#pragma unroll
      for (int ii = 0; ii < 4; ++ii)
#pragma unroll
        for (int jj = 0; jj < 4; ++jj)
          acc[ii][jj] = fmaf(aa[ii], bb[jj], acc[ii][jj]);
    }
  }

  if (MODE == 0) {
#pragma unroll
    for (int ii = 0; ii < 4; ++ii) {
      int m = m0 + ty * 4 + ii;
      int col = n0 + tx * 4;
      float4 v;
      v.x = acc[ii][0] + b1[col + 0];
      v.y = acc[ii][1] + b1[col + 1];
      v.z = acc[ii][2] + b1[col + 2];
      v.w = acc[ii][3] + b1[col + 3];
      *reinterpret_cast<float4*>(outA + (size_t)m * NI + col) = v;
    }
  } else {
    // c4[b][i4][t], float4 packs 4 consecutive i
    int b = m0 >> 8;
    int t0 = (m0 & (NL - 1)) + ty * 4;
    int i4 = (n0 >> 2) + tx;
#pragma unroll
    for (int ii = 0; ii < 4; ++ii) {
      float4 v;
      v.x = acc[ii][0];
      v.y = acc[ii][1];
      v.z = acc[ii][2];
      v.w = acc[ii][3];
      outC4[((size_t)b * NI4 + i4) * NL + t0 + ii] = v;
    }
  }
}

// ---------------------------------------------------------------------------
// Kernel 3: span logits. Block = (b,s) with 1024 threads: t = tid&255,
// q = tid>>8 takes one quarter of the i-range. LDS tree-sum at the end.
// ---------------------------------------------------------------------------
__global__ __launch_bounds__(1024) void span_kernel(
    const float4* __restrict__ a4,    // [M][NI4], b1 folded
    const float4* __restrict__ c4,    // [B][NI4][NL]
    const float4* __restrict__ w24,
    const float* __restrict__ b2,
    float* __restrict__ out) {
  int bs = blockIdx.x;     // b*L + s
  int b = bs >> 8;
  int tid = threadIdx.x;
  int t = tid & 255;
  int q = tid >> 8;        // 0..3

  __shared__ float4 a_lds[NI4];
  __shared__ float4 w_lds[NI4];
  __shared__ float red[4][NL];

  for (int i = tid; i < NI4; i += 1024) {
    a_lds[i] = a4[(size_t)bs * NI4 + i];
    w_lds[i] = w24[i];
  }
  __syncthreads();

  const float4* cb = c4 + (size_t)b * NI4 * NL + t;
  float acc = 0.f;
  const int i4_0 = q * (NI4 / 4);        // 96 groups per quarter
#pragma unroll 4
  for (int i4 = i4_0; i4 < i4_0 + NI4 / 4; ++i4) {
    float4 cv = cb[(size_t)i4 * NL];
    float4 av = a_lds[i4];
    float4 wv = w_lds[i4];
    float g0 = fast_gelu(av.x + cv.x);
    float g1 = fast_gelu(av.y + cv.y);
    float g2 = fast_gelu(av.z + cv.z);
    float g3 = fast_gelu(av.w + cv.w);
    acc = fmaf(g0, wv.x, acc);
    acc = fmaf(g1, wv.y, acc);
    acc = fmaf(g2, wv.z, acc);
    acc = fmaf(g3, wv.w, acc);
  }
  red[q][t] = acc;
  __syncthreads();
  if (tid < NL) {
    float s = red[0][tid] + red[1][tid] + red[2][tid] + red[3][tid];
    out[2 * NM + (size_t)bs * NL + tid] = s + b2[0];
  }
}

// ---------------------------------------------------------------------------
extern "C" void kernel_launch(void* const* d_in, const int* in_sizes, int n_in,
                              void* d_out, int out_size, void* d_ws, size_t ws_size,
                              hipStream_t stream) {
  const float* hs = (const float*)d_in[0];
  const float* sw = (const float*)d_in[1];
  const float* sb = (const float*)d_in[2];
  const float* ew = (const float*)d_in[3];
  const float* eb = (const float*)d_in[4];
  const float* w1 = (const float*)d_in[5];
  const float* b1 = (const float*)d_in[6];
  const float* w2 = (const float*)d_in[7];
  const float* b2 = (const float*)d_in[8];
  float* out = (float*)d_out;

  float* a  = (float*)d_ws;                          // M*I floats = 3 MB
  float4* c4 = (float4*)((float*)d_ws + (size_t)NM * NI);  // B*NI4*NL float4 = 3 MB

  logits_kernel<<<NM, 256, 0, stream>>>(hs, sw, sb, ew, eb, out);

  dim3 ggrid(NM / 64, NI / 64, 2);
  gemm_kernel<<<ggrid, 256, 0, stream>>>(hs, w1, b1, a, c4);

  span_kernel<<<NM, 1024, 0, stream>>>((const float4*)a, c4, (const float4*)w2, b2, out);
}

// Round 3
// 90.949 us; speedup vs baseline: 3.4502x; 1.3105x over previous
//
#include <hip/hip_runtime.h>
#include <math.h>

#define NB 2
#define NL 256
#define NH 768
#define NI 1536
#define NM (NB * NL)   // 512

typedef __attribute__((ext_vector_type(8))) short bf16x8;
typedef __attribute__((ext_vector_type(4))) float f32x4;

// ---------------------------------------------------------------------------
// fast gelu: x * sigmoid(1.5957691(x + 0.044715 x^3)) via exp2
// ---------------------------------------------------------------------------
#if __has_builtin(__builtin_amdgcn_exp2f)
#define FAST_EXP2(x) __builtin_amdgcn_exp2f(x)
#else
#define FAST_EXP2(x) exp2f(x)
#endif
#if __has_builtin(__builtin_amdgcn_rcpf)
#define FAST_RCP(x) __builtin_amdgcn_rcpf(x)
#else
#define FAST_RCP(x) (1.0f / (x))
#endif

__device__ __forceinline__ float fast_gelu(float x) {
  float u = x * x;
  float zn = x * fmaf(u, -0.1029434f, -2.3022082f);
  float e = FAST_EXP2(zn);
  return x * FAST_RCP(1.0f + e);
}

// fp32 -> bf16 round-to-nearest-even, packed pair
__device__ __forceinline__ unsigned short f2bf(float f) {
  unsigned int u = __builtin_bit_cast(unsigned int, f);
  u += 0x7FFFu + ((u >> 16) & 1u);
  return (unsigned short)(u >> 16);
}
__device__ __forceinline__ unsigned int pack2(float lo, float hi) {
  return (unsigned int)f2bf(lo) | ((unsigned int)f2bf(hi) << 16);
}

// ---------------------------------------------------------------------------
// Kernel 1: start/end logits. One block per row m, 256 threads.
// ---------------------------------------------------------------------------
__global__ __launch_bounds__(256) void logits_kernel(
    const float* __restrict__ hs,
    const float* __restrict__ sw, const float* __restrict__ sb,
    const float* __restrict__ ew, const float* __restrict__ eb,
    float* __restrict__ out) {
  int m = blockIdx.x;
  int tid = threadIdx.x;
  const float* row = hs + (size_t)m * NH;
  float accs = 0.f, acce = 0.f;
  for (int h = tid; h < NH; h += 256) {
    float v = row[h];
    accs = fmaf(v, sw[h], accs);
    acce = fmaf(v, ew[h], acce);
  }
  for (int off = 32; off > 0; off >>= 1) {
    accs += __shfl_down(accs, off, 64);
    acce += __shfl_down(acce, off, 64);
  }
  __shared__ float s_s[4], s_e[4];
  int wid = tid >> 6;
  if ((tid & 63) == 0) { s_s[wid] = accs; s_e[wid] = acce; }
  __syncthreads();
  if (tid == 0) {
    float ts = s_s[0] + s_s[1] + s_s[2] + s_s[3];
    float te = s_e[0] + s_e[1] + s_e[2] + s_e[3];
    out[m]      = ts + sb[0];
    out[NM + m] = te + eb[0];
  }
}

// ---------------------------------------------------------------------------
// Kernel 2: bf16 MFMA GEMM.  C(M x N) = hs(M x 768) @ W(768 x 1536)
// mode = blockIdx.z: 0 -> aOut[m][n] (+b1);  1 -> cT[b][i=n][t=m] (dwordx4)
// Block: 256 thr = 4 waves (2 m x 2 n), tile 64x128, BK=32, 16x16x32 mfma.
// LDS: [row][32 bf16] rows of 64B = 4 x 16B slots, slot ^= (row&3) swizzle
// (bijective within row; frag reads cover 16 full rows -> conflict-free).
// ---------------------------------------------------------------------------
__global__ __launch_bounds__(256) void gemm_mfma(
    const float* __restrict__ hs, const float* __restrict__ w1,
    const float* __restrict__ b1, float* __restrict__ aOut,
    float* __restrict__ cT) {
  constexpr int BM = 64, BN = 128, BK = 32;
  __shared__ short A_lds[BM * BK];   // [64][32] swizzled
  __shared__ short B_lds[BN * BK];   // [n][k] = [128][32] swizzled

  const int mode = blockIdx.z;
  const float* __restrict__ W = w1 + (size_t)mode * NH * NI;
  const int m0 = blockIdx.x * BM;
  const int n0 = blockIdx.y * BN;
  const int tid = threadIdx.x;
  const int lane = tid & 63;
  const int wid = tid >> 6;
  const int wr = wid >> 1, wc = wid & 1;

  // staging maps
  const int ar  = tid >> 2;          // A row 0..63
  const int akq = (tid & 3) * 8;     // A k-offset {0,8,16,24}
  const int bkq = (tid >> 5) * 4;    // B k-offset {0,4,...,28}
  const int bnl = tid & 31;          // B n-lane (strided n = bnl + nn*32)

  f32x4 acc[2][4] = {};              // [m-tile][n-tile]

  for (int k0 = 0; k0 < NH; k0 += BK) {
    // global loads
    const float* pa = hs + (size_t)(m0 + ar) * NH + k0 + akq;
    float4 a0 = *reinterpret_cast<const float4*>(pa);
    float4 a1 = *reinterpret_cast<const float4*>(pa + 4);
    float bv[4][4];
#pragma unroll
    for (int j = 0; j < 4; ++j) {
      const float* pb = W + (size_t)(k0 + bkq + j) * NI + n0 + bnl;
#pragma unroll
      for (int nn = 0; nn < 4; ++nn) bv[j][nn] = pb[nn * 32];
    }
    __syncthreads();
    // LDS writes (swizzled)
    {
      int4 v;
      v.x = (int)pack2(a0.x, a0.y);
      v.y = (int)pack2(a0.z, a0.w);
      v.z = (int)pack2(a1.x, a1.y);
      v.w = (int)pack2(a1.z, a1.w);
      const int off = ar * 64 + (((akq >> 3) ^ (ar & 3)) << 4);
      *reinterpret_cast<int4*>(reinterpret_cast<char*>(A_lds) + off) = v;
    }
#pragma unroll
    for (int nn = 0; nn < 4; ++nn) {
      const int n = bnl + nn * 32;
      uint2 v;
      v.x = pack2(bv[0][nn], bv[1][nn]);
      v.y = pack2(bv[2][nn], bv[3][nn]);
      const int off = n * 64 + (((bkq >> 3) ^ (n & 3)) << 4) + ((bkq & 4) << 1);
      *reinterpret_cast<uint2*>(reinterpret_cast<char*>(B_lds) + off) = v;
    }
    __syncthreads();
    // fragments + MFMA
    const int lr = lane & 15, ls = lane >> 4;
    bf16x8 af[2], bf[4];
#pragma unroll
    for (int mt = 0; mt < 2; ++mt) {
      const int row = wr * 32 + mt * 16 + lr;
      const int off = row * 64 + ((ls ^ (row & 3)) << 4);
      af[mt] = *reinterpret_cast<const bf16x8*>(reinterpret_cast<const char*>(A_lds) + off);
    }
#pragma unroll
    for (int nt = 0; nt < 4; ++nt) {
      const int nrow = wc * 64 + nt * 16 + lr;
      const int off = nrow * 64 + ((ls ^ (nrow & 3)) << 4);
      bf[nt] = *reinterpret_cast<const bf16x8*>(reinterpret_cast<const char*>(B_lds) + off);
    }
#pragma unroll
    for (int mt = 0; mt < 2; ++mt)
#pragma unroll
      for (int nt = 0; nt < 4; ++nt)
        acc[mt][nt] = __builtin_amdgcn_mfma_f32_16x16x32_bf16(af[mt], bf[nt], acc[mt][nt], 0, 0, 0);
  }

  // epilogue: C/D layout (m89-verified): col = lane&15, row = (lane>>4)*4 + reg
  const int lr = lane & 15, lq = lane >> 4;
  if (mode == 0) {
#pragma unroll
    for (int nt = 0; nt < 4; ++nt) {
      const int n = n0 + wc * 64 + nt * 16 + lr;
      const float bias = b1[n];
#pragma unroll
      for (int mt = 0; mt < 2; ++mt) {
        const int mb = m0 + wr * 32 + mt * 16 + lq * 4;
#pragma unroll
        for (int r = 0; r < 4; ++r)
          aOut[(size_t)(mb + r) * NI + n] = acc[mt][nt][r] + bias;
      }
    }
  } else {
    const int b = m0 >> 8;
    const int tb = (m0 & (NL - 1)) + wr * 32;
#pragma unroll
    for (int nt = 0; nt < 4; ++nt) {
      const int i = n0 + wc * 64 + nt * 16 + lr;
      float* dst = cT + (size_t)b * NI * NL + (size_t)i * NL + tb;
#pragma unroll
      for (int mt = 0; mt < 2; ++mt)
        *reinterpret_cast<f32x4*>(dst + mt * 16 + lq * 4) = acc[mt][nt];
    }
  }
}

// ---------------------------------------------------------------------------
// Kernel 3: span logits. Block = (b,s), 1024 threads: t4 = tid&63 (4 t's),
// q = tid>>6 (16 i-chunks of 96). cT is [b][i][t]: float4-of-t loads,
// a/w2 interleaved as float2 in LDS (one broadcast ds_read_b64 per i).
// ---------------------------------------------------------------------------
__global__ __launch_bounds__(1024) void span_kernel(
    const float* __restrict__ aRow,   // [M][I], b1 folded
    const float* __restrict__ cT,     // [B][I][L]
    const float* __restrict__ w2,
    const float* __restrict__ b2,
    float* __restrict__ out) {
  const int bs = blockIdx.x;
  const int b = bs >> 8;
  const int tid = threadIdx.x;
  const int t4 = tid & 63;
  const int q = tid >> 6;            // 0..15

  __shared__ float2 aw[NI];          // 12 KB
  __shared__ float4 red[16][64];     // 16 KB

  for (int i = tid; i < NI; i += 1024)
    aw[i] = make_float2(aRow[(size_t)bs * NI + i], w2[i]);
  __syncthreads();

  const float4* cb = reinterpret_cast<const float4*>(cT + (size_t)b * NI * NL) + t4;
  float4 acc = make_float4(0.f, 0.f, 0.f, 0.f);
  const int i0 = q * (NI / 16);      // 96 i per chunk
#pragma unroll 4
  for (int i = i0; i < i0 + NI / 16; ++i) {
    float4 cv = cb[(size_t)i * (NL / 4)];
    float2 awv = aw[i];
    float a = awv.x, w = awv.y;
    acc.x = fmaf(fast_gelu(a + cv.x), w, acc.x);
    acc.y = fmaf(fast_gelu(a + cv.y), w, acc.y);
    acc.z = fmaf(fast_gelu(a + cv.z), w, acc.z);
    acc.w = fmaf(fast_gelu(a + cv.w), w, acc.w);
  }
  red[q][t4] = acc;
  __syncthreads();
  if (tid < 64) {
    float4 s = make_float4(0.f, 0.f, 0.f, 0.f);
#pragma unroll
    for (int qq = 0; qq < 16; ++qq) {
      float4 v = red[qq][tid];
      s.x += v.x; s.y += v.y; s.z += v.z; s.w += v.w;
    }
    const float bb = b2[0];
    float4 o;
    o.x = s.x + bb; o.y = s.y + bb; o.z = s.z + bb; o.w = s.w + bb;
    *reinterpret_cast<float4*>(out + 2 * NM + (size_t)bs * NL + tid * 4) = o;
  }
}

// ---------------------------------------------------------------------------
extern "C" void kernel_launch(void* const* d_in, const int* in_sizes, int n_in,
                              void* d_out, int out_size, void* d_ws, size_t ws_size,
                              hipStream_t stream) {
  const float* hs = (const float*)d_in[0];
  const float* sw = (const float*)d_in[1];
  const float* sb = (const float*)d_in[2];
  const float* ew = (const float*)d_in[3];
  const float* eb = (const float*)d_in[4];
  const float* w1 = (const float*)d_in[5];
  const float* b1 = (const float*)d_in[6];
  const float* w2 = (const float*)d_in[7];
  const float* b2 = (const float*)d_in[8];
  float* out = (float*)d_out;

  float* a  = (float*)d_ws;                           // M*I floats = 3 MB
  float* cT = (float*)d_ws + (size_t)NM * NI;         // B*I*L floats = 3 MB

  logits_kernel<<<NM, 256, 0, stream>>>(hs, sw, sb, ew, eb, out);

  dim3 ggrid(NM / 64, NI / 128, 2);
  gemm_mfma<<<ggrid, 256, 0, stream>>>(hs, w1, b1, a, cT);

  span_kernel<<<NM, 1024, 0, stream>>>(a, cT, w2, b2, out);
}

// Round 4
// 88.319 us; speedup vs baseline: 3.5529x; 1.0298x over previous
//
#include <hip/hip_runtime.h>
#include <math.h>

#define NB 2
#define NL 256
#define NH 768
#define NI 1536
#define NM (NB * NL)   // 512

typedef __attribute__((ext_vector_type(8))) short bf16x8;
typedef __attribute__((ext_vector_type(4))) float f32x4;
typedef __attribute__((ext_vector_type(2))) float f32x2;

#if __has_builtin(__builtin_amdgcn_exp2f)
#define FAST_EXP2(x) __builtin_amdgcn_exp2f(x)
#else
#define FAST_EXP2(x) exp2f(x)
#endif
#if __has_builtin(__builtin_amdgcn_rcpf)
#define FAST_RCP(x) __builtin_amdgcn_rcpf(x)
#else
#define FAST_RCP(x) (1.0f / (x))
#endif

// fp32 -> bf16 round-to-nearest-even, packed pair
__device__ __forceinline__ unsigned short f2bf(float f) {
  unsigned int u = __builtin_bit_cast(unsigned int, f);
  u += 0x7FFFu + ((u >> 16) & 1u);
  return (unsigned short)(u >> 16);
}
__device__ __forceinline__ unsigned int pack2(float lo, float hi) {
  return (unsigned int)f2bf(lo) | ((unsigned int)f2bf(hi) << 16);
}

// ---------------------------------------------------------------------------
// Kernel 1: start/end logits. One block per row m, 256 threads.
// ---------------------------------------------------------------------------
__global__ __launch_bounds__(256) void logits_kernel(
    const float* __restrict__ hs,
    const float* __restrict__ sw, const float* __restrict__ sb,
    const float* __restrict__ ew, const float* __restrict__ eb,
    float* __restrict__ out) {
  int m = blockIdx.x;
  int tid = threadIdx.x;
  const float* row = hs + (size_t)m * NH;
  float accs = 0.f, acce = 0.f;
  for (int h = tid; h < NH; h += 256) {
    float v = row[h];
    accs = fmaf(v, sw[h], accs);
    acce = fmaf(v, ew[h], acce);
  }
  for (int off = 32; off > 0; off >>= 1) {
    accs += __shfl_down(accs, off, 64);
    acce += __shfl_down(acce, off, 64);
  }
  __shared__ float s_s[4], s_e[4];
  int wid = tid >> 6;
  if ((tid & 63) == 0) { s_s[wid] = accs; s_e[wid] = acce; }
  __syncthreads();
  if (tid == 0) {
    float ts = s_s[0] + s_s[1] + s_s[2] + s_s[3];
    float te = s_e[0] + s_e[1] + s_e[2] + s_e[3];
    out[m]      = ts + sb[0];
    out[NM + m] = te + eb[0];
  }
}

// ---------------------------------------------------------------------------
// Kernel 2: bf16 MFMA GEMM.  C(M x N) = hs(M x 768) @ W(768 x 1536)
// mode = blockIdx.z: 0 -> aOut[m][n] (+b1);  1 -> cT[b][i=n][t=m]
// Tile 64x96, BK=32, 4 waves (2m x 2n, 48 n per wave), grid (8,16,2) = 256
// blocks = exactly 1 per CU.
// LDS rows of 64B = 4 x 16B slots, slot ^= (row&3) swizzle.
// ---------------------------------------------------------------------------
__global__ __launch_bounds__(256) void gemm_mfma(
    const float* __restrict__ hs, const float* __restrict__ w1,
    const float* __restrict__ b1, float* __restrict__ aOut,
    float* __restrict__ cT) {
  constexpr int BM = 64, BN = 96, BK = 32;
  __shared__ short A_lds[BM * BK];   // [64][32] swizzled
  __shared__ short B_lds[BN * BK];   // [n][k] = [96][32] swizzled

  const int mode = blockIdx.z;
  const float* __restrict__ W = w1 + (size_t)mode * NH * NI;
  const int m0 = blockIdx.x * BM;
  const int n0 = blockIdx.y * BN;
  const int tid = threadIdx.x;
  const int lane = tid & 63;
  const int wid = tid >> 6;
  const int wr = wid >> 1, wc = wid & 1;

  const int ar  = tid >> 2;          // A row 0..63
  const int akq = (tid & 3) * 8;     // A k-offset {0,8,16,24}
  const int bkq = (tid >> 5) * 4;    // B k-offset {0,4,...,28}
  const int bnl = tid & 31;          // B n-lane (n = bnl + nn*32, nn<3)

  f32x4 acc[2][3] = {};              // [m-tile][n-tile]

  for (int k0 = 0; k0 < NH; k0 += BK) {
    const float* pa = hs + (size_t)(m0 + ar) * NH + k0 + akq;
    float4 a0 = *reinterpret_cast<const float4*>(pa);
    float4 a1 = *reinterpret_cast<const float4*>(pa + 4);
    float bv[4][3];
#pragma unroll
    for (int j = 0; j < 4; ++j) {
      const float* pb = W + (size_t)(k0 + bkq + j) * NI + n0 + bnl;
#pragma unroll
      for (int nn = 0; nn < 3; ++nn) bv[j][nn] = pb[nn * 32];
    }
    __syncthreads();
    {
      int4 v;
      v.x = (int)pack2(a0.x, a0.y);
      v.y = (int)pack2(a0.z, a0.w);
      v.z = (int)pack2(a1.x, a1.y);
      v.w = (int)pack2(a1.z, a1.w);
      const int off = ar * 64 + (((akq >> 3) ^ (ar & 3)) << 4);
      *reinterpret_cast<int4*>(reinterpret_cast<char*>(A_lds) + off) = v;
    }
#pragma unroll
    for (int nn = 0; nn < 3; ++nn) {
      const int n = bnl + nn * 32;
      uint2 v;
      v.x = pack2(bv[0][nn], bv[1][nn]);
      v.y = pack2(bv[2][nn], bv[3][nn]);
      const int off = n * 64 + (((bkq >> 3) ^ (n & 3)) << 4) + ((bkq & 4) << 1);
      *reinterpret_cast<uint2*>(reinterpret_cast<char*>(B_lds) + off) = v;
    }
    __syncthreads();
    const int lr = lane & 15, ls = lane >> 4;
    bf16x8 af[2], bf[3];
#pragma unroll
    for (int mt = 0; mt < 2; ++mt) {
      const int row = wr * 32 + mt * 16 + lr;
      const int off = row * 64 + ((ls ^ (row & 3)) << 4);
      af[mt] = *reinterpret_cast<const bf16x8*>(reinterpret_cast<const char*>(A_lds) + off);
    }
#pragma unroll
    for (int nt = 0; nt < 3; ++nt) {
      const int nrow = wc * 48 + nt * 16 + lr;
      const int off = nrow * 64 + ((ls ^ (nrow & 3)) << 4);
      bf[nt] = *reinterpret_cast<const bf16x8*>(reinterpret_cast<const char*>(B_lds) + off);
    }
#pragma unroll
    for (int mt = 0; mt < 2; ++mt)
#pragma unroll
      for (int nt = 0; nt < 3; ++nt)
        acc[mt][nt] = __builtin_amdgcn_mfma_f32_16x16x32_bf16(af[mt], bf[nt], acc[mt][nt], 0, 0, 0);
  }

  // C/D layout: col = lane&15, row = (lane>>4)*4 + reg
  const int lr = lane & 15, lq = lane >> 4;
  if (mode == 0) {
#pragma unroll
    for (int nt = 0; nt < 3; ++nt) {
      const int n = n0 + wc * 48 + nt * 16 + lr;
      const float bias = b1[n];
#pragma unroll
      for (int mt = 0; mt < 2; ++mt) {
        const int mb = m0 + wr * 32 + mt * 16 + lq * 4;
#pragma unroll
        for (int r = 0; r < 4; ++r)
          aOut[(size_t)(mb + r) * NI + n] = acc[mt][nt][r] + bias;
      }
    }
  } else {
    const int b = m0 >> 8;
    const int tb = (m0 & (NL - 1)) + wr * 32;
#pragma unroll
    for (int nt = 0; nt < 3; ++nt) {
      const int i = n0 + wc * 48 + nt * 16 + lr;
      float* dst = cT + (size_t)b * NI * NL + (size_t)i * NL + tb;
#pragma unroll
      for (int mt = 0; mt < 2; ++mt)
        *reinterpret_cast<f32x4*>(dst + mt * 16 + lq * 4) = acc[mt][nt];
    }
  }
}

// ---------------------------------------------------------------------------
// Kernel 3: span logits. Block = (b,s), 1024 threads: t4 = tid&63, q = tid>>6.
// gelu via exp2 + ONE rcp per 4 elements (batched reciprocal, exact), and
// float2 vector ops to enable v_pk_{add,mul,fma}_f32 codegen.
// ---------------------------------------------------------------------------
__global__ __launch_bounds__(1024) void span_kernel(
    const float* __restrict__ aRow,   // [M][I], b1 folded
    const float* __restrict__ cT,     // [B][I][L]
    const float* __restrict__ w2,
    const float* __restrict__ b2,
    float* __restrict__ out) {
  const int bs = blockIdx.x;
  const int b = bs >> 8;
  const int tid = threadIdx.x;
  const int t4 = tid & 63;
  const int q = tid >> 6;            // 0..15

  __shared__ float2 aw[NI];          // 12 KB
  __shared__ float4 red[16][64];     // 16 KB

  for (int i = tid; i < NI; i += 1024)
    aw[i] = make_float2(aRow[(size_t)bs * NI + i], w2[i]);
  __syncthreads();

  const float4* cb = reinterpret_cast<const float4*>(cT + (size_t)b * NI * NL) + t4;
  f32x2 acc01 = {0.f, 0.f}, acc23 = {0.f, 0.f};
  const f32x2 C1 = {-2.3022082f, -2.3022082f};   // -log2(e)*1.5957691
  const f32x2 C2 = {-0.1029434f, -0.1029434f};   // -log2(e)*1.5957691*0.044715
  const int i0 = q * (NI / 16);      // 96 i per chunk
#pragma unroll 4
  for (int i = i0; i < i0 + NI / 16; ++i) {
    float4 cv = cb[(size_t)i * (NL / 4)];
    float2 awv = aw[i];
    f32x2 av = {awv.x, awv.x};
    f32x2 wv = {awv.y, awv.y};
    f32x2 x01 = av + (f32x2){cv.x, cv.y};
    f32x2 x23 = av + (f32x2){cv.z, cv.w};
    // zn = x * (C1 + C2*x^2)  (tanh-form gelu, sigmoid representation)
    f32x2 u01 = x01 * x01, u23 = x23 * x23;
    f32x2 p01 = C2 * u01 + C1, p23 = C2 * u23 + C1;
    f32x2 zn01 = x01 * p01, zn23 = x23 * p23;
    f32x2 d01, d23;
    d01.x = FAST_EXP2(zn01.x) + 1.0f;
    d01.y = FAST_EXP2(zn01.y) + 1.0f;
    d23.x = FAST_EXP2(zn23.x) + 1.0f;
    d23.y = FAST_EXP2(zn23.y) + 1.0f;
    // one rcp for all four: r = 1/(d0 d1 d2 d3), reconstruct 1/d_k exactly
    float m01 = d01.x * d01.y;
    float m23 = d23.x * d23.y;
    float r = FAST_RCP(m01 * m23);
    float r01 = r * m23;               // 1/m01
    float r23 = r * m01;               // 1/m23
    f32x2 s01 = {r01 * d01.y, r01 * d01.x};   // {1/d0, 1/d1}
    f32x2 s23 = {r23 * d23.y, r23 * d23.x};
    f32x2 xw01 = x01 * wv, xw23 = x23 * wv;
    acc01 += xw01 * s01;
    acc23 += xw23 * s23;
  }
  red[q][t4] = make_float4(acc01.x, acc01.y, acc23.x, acc23.y);
  __syncthreads();
  if (tid < 64) {
    float4 s = make_float4(0.f, 0.f, 0.f, 0.f);
#pragma unroll
    for (int qq = 0; qq < 16; ++qq) {
      float4 v = red[qq][tid];
      s.x += v.x; s.y += v.y; s.z += v.z; s.w += v.w;
    }
    const float bb = b2[0];
    float4 o;
    o.x = s.x + bb; o.y = s.y + bb; o.z = s.z + bb; o.w = s.w + bb;
    *reinterpret_cast<float4*>(out + 2 * NM + (size_t)bs * NL + tid * 4) = o;
  }
}

// ---------------------------------------------------------------------------
extern "C" void kernel_launch(void* const* d_in, const int* in_sizes, int n_in,
                              void* d_out, int out_size, void* d_ws, size_t ws_size,
                              hipStream_t stream) {
  const float* hs = (const float*)d_in[0];
  const float* sw = (const float*)d_in[1];
  const float* sb = (const float*)d_in[2];
  const float* ew = (const float*)d_in[3];
  const float* eb = (const float*)d_in[4];
  const float* w1 = (const float*)d_in[5];
  const float* b1 = (const float*)d_in[6];
  const float* w2 = (const float*)d_in[7];
  const float* b2 = (const float*)d_in[8];
  float* out = (float*)d_out;

  float* a  = (float*)d_ws;                           // M*I floats = 3 MB
  float* cT = (float*)d_ws + (size_t)NM * NI;         // B*I*L floats = 3 MB

  logits_kernel<<<NM, 256, 0, stream>>>(hs, sw, sb, ew, eb, out);

  dim3 ggrid(NM / 64, NI / 96, 2);
  gemm_mfma<<<ggrid, 256, 0, stream>>>(hs, w1, b1, a, cT);

  span_kernel<<<NM, 1024, 0, stream>>>(a, cT, w2, b2, out);
}